// Round 1
// baseline (67.490 us; speedup 1.0000x reference)
//
#include <hip/hip_runtime.h>

// StraightRenderer: G=512, S=32 strokes x P=8 points -> 224 segments.
// out[i,j] = min(1, min over segments of dist((i,j), seg)/(2*t_stroke))
// Computed as sqrt(min over segments of dist^2 * scale_stroke), scale = 1/(4t^2).

#define NSEG 224

__global__ __launch_bounds__(256) void render_kernel(
    const float* __restrict__ strokes,   // [32,8,2] in [0,1]
    const float* __restrict__ thick,     // [32]
    float* __restrict__ out)             // [512,512]
{
    __shared__ float4 sseg[NSEG];   // vx, vy, ex, ey (pixel coords)
    __shared__ float2 smul[NSEG];   // 1/(|e|^2+1e-5), 1/(4 t^2)
    const int tid = threadIdx.x;

    // Preamble: one thread per segment builds the table (block-redundant, tiny).
    if (tid < NSEG) {
        const int s = tid / 7;
        const int k = tid - s * 7;
        const int base = (s * 8 + k) * 2;   // strokes[s][k][0]
        float ax = strokes[base + 0];
        float ay = strokes[base + 1];
        float bx = strokes[base + 2];
        float by = strokes[base + 3];
        ax = fminf(fmaxf(ax, 0.0f), 1.0f) * 512.0f;
        ay = fminf(fmaxf(ay, 0.0f), 1.0f) * 512.0f;
        bx = fminf(fmaxf(bx, 0.0f), 1.0f) * 512.0f;
        by = fminf(fmaxf(by, 0.0f), 1.0f) * 512.0f;
        const float ex = bx - ax;
        const float ey = by - ay;
        const float d2 = ex * ex + ey * ey;
        const float t  = fmaxf(thick[s] * 2.0f + 0.5f, 0.5f);
        sseg[tid] = make_float4(ax, ay, ex, ey);
        smul[tid] = make_float2(1.0f / (d2 + 1e-5f), 1.0f / (4.0f * t * t));
    }
    __syncthreads();

    // 2 consecutive pixels (same x = row i, adjacent y = cols j, j+1) per thread.
    const int n   = (blockIdx.x * 256 + tid) * 2;   // linear index into [512,512]
    const float px  = (float)(n >> 9);              // i (x coordinate per meshgrid 'ij')
    const float py0 = (float)(n & 511);             // j
    const float py1 = py0 + 1.0f;

    float acc0 = 1e30f, acc1 = 1e30f;
#pragma unroll 4
    for (int g = 0; g < NSEG; ++g) {
        const float4 sg = sseg[g];   // broadcast ds_read_b128
        const float2 ms = smul[g];   // broadcast ds_read_b64
        const float pvx  = px  - sg.x;
        const float pvy0 = py0 - sg.y;
        const float pvy1 = py1 - sg.y;
        const float pe   = pvx * sg.z;          // shared across the 2 pixels
        float f0 = fmaf(pvy0, sg.w, pe) * ms.x;
        float f1 = fmaf(pvy1, sg.w, pe) * ms.x;
        f0 = fminf(fmaxf(f0, 0.0f), 1.0f);      // folds to v_med3_f32
        f1 = fminf(fmaxf(f1, 0.0f), 1.0f);
        const float dx0 = fmaf(-f0, sg.z, pvx);
        const float dy0 = fmaf(-f0, sg.w, pvy0);
        const float dx1 = fmaf(-f1, sg.z, pvx);
        const float dy1 = fmaf(-f1, sg.w, pvy1);
        const float q0 = fmaf(dy0, dy0, dx0 * dx0);
        const float q1 = fmaf(dy1, dy1, dx1 * dx1);
        acc0 = fminf(acc0, q0 * ms.y);
        acc1 = fminf(acc1, q1 * ms.y);
    }

    const float o0 = fminf(sqrtf(acc0), 1.0f);
    const float o1 = fminf(sqrtf(acc1), 1.0f);
    *reinterpret_cast<float2*>(out + n) = make_float2(o0, o1);  // n even -> 8B aligned
}

extern "C" void kernel_launch(void* const* d_in, const int* in_sizes, int n_in,
                              void* d_out, int out_size, void* d_ws, size_t ws_size,
                              hipStream_t stream) {
    const float* strokes = (const float*)d_in[0];
    const float* thick   = (const float*)d_in[1];
    float* out = (float*)d_out;
    // 262144 pixels / 2 per thread / 256 threads = 512 blocks
    hipLaunchKernelGGL(render_kernel, dim3(512), dim3(256), 0, stream,
                       strokes, thick, out);
}

// Round 2
// 55.926 us; speedup vs baseline: 1.2068x; 1.2068x over previous
//
#include <hip/hip_runtime.h>

// StraightRenderer: G=512, S=32 strokes x P=8 points -> 224 segments.
// out[i,j] = min(1, min_seg dist((i,j),seg)/(2*t_stroke))
//          = min(1, sqrt(min_seg dist^2 * scale_stroke)), scale = 1/(4t^2).
//
// Key: output clamps at 1.0 and 2t <= 5 px, so a segment only matters within
// 5 px of itself. Tile the canvas 16x32 px per block; cull segments against
// the tile bounding circle (r = 17.22 px) + 2t; compact survivors into LDS.
// Expected survivors ~12-25 of 224 -> ~10x less inner-loop work.

#define NSEG 224
#define TILE_I 16   // rows (i = x in meshgrid 'ij') per tile
#define TILE_J 32   // cols (j = y) per tile
// grid: 16 j-tiles x 32 i-tiles = 512 blocks, 256 threads, 2 px/thread

__global__ __launch_bounds__(256) void render_kernel(
    const float* __restrict__ strokes,   // [32,8,2] in [0,1]
    const float* __restrict__ thick,     // [32]
    float* __restrict__ out)             // [512,512]
{
    __shared__ float4 sseg[NSEG];   // vx, vy, ex, ey (kept segments, compacted)
    __shared__ float2 smul[NSEG];   // 1/(|e|^2+1e-5), 1/(4 t^2)
    __shared__ int cnt;
    const int tid = threadIdx.x;

    const int tile_j = blockIdx.x & 15;   // 16 tiles across j
    const int tile_i = blockIdx.x >> 4;   // 32 tiles across i
    const int i0 = tile_i * TILE_I;
    const int j0 = tile_j * TILE_J;
    // tile pixel centers span [i0, i0+15] x [j0, j0+31]
    const float ccx = (float)i0 + 7.5f;
    const float ccy = (float)j0 + 15.5f;
    // half-diagonal = sqrt(7.5^2 + 15.5^2) = 17.22; margin to 18.0

    if (tid == 0) cnt = 0;
    __syncthreads();

    if (tid < NSEG) {
        const int s = tid / 7;
        const int k = tid - s * 7;
        const int base = (s * 8 + k) * 2;
        float ax = strokes[base + 0];
        float ay = strokes[base + 1];
        float bx = strokes[base + 2];
        float by = strokes[base + 3];
        ax = fminf(fmaxf(ax, 0.0f), 1.0f) * 512.0f;
        ay = fminf(fmaxf(ay, 0.0f), 1.0f) * 512.0f;
        bx = fminf(fmaxf(bx, 0.0f), 1.0f) * 512.0f;
        by = fminf(fmaxf(by, 0.0f), 1.0f) * 512.0f;
        const float ex = bx - ax;
        const float ey = by - ay;
        const float d2 = ex * ex + ey * ey;
        const float inv = 1.0f / (d2 + 1e-5f);
        const float t  = fmaxf(thick[s] * 2.0f + 0.5f, 0.5f);
        // cull: distance from tile center to segment vs (2t + r + slack)
        const float pvx = ccx - ax;
        const float pvy = ccy - ay;
        float f = fmaf(pvy, ey, pvx * ex) * inv;
        f = fminf(fmaxf(f, 0.0f), 1.0f);
        const float dx = fmaf(-f, ex, pvx);
        const float dy = fmaf(-f, ey, pvy);
        const float d2c = fmaf(dy, dy, dx * dx);
        const float thr = 2.0f * t + 18.0f;
        if (d2c < thr * thr) {
            const int idx = atomicAdd(&cnt, 1);   // order-independent (min)
            sseg[idx] = make_float4(ax, ay, ex, ey);
            smul[idx] = make_float2(inv, 1.0f / (4.0f * t * t));
        }
    }
    __syncthreads();
    const int n_kept = cnt;

    // 2 consecutive-j pixels per thread: 16 threads/row x 2 px = 32 cols, 16 rows
    const int pi = i0 + (tid >> 4);
    const int pj = j0 + ((tid & 15) << 1);
    const float px  = (float)pi;
    const float py0 = (float)pj;
    const float py1 = py0 + 1.0f;

    float acc0 = 4.0f, acc1 = 4.0f;   // sqrt(4)=2 -> clamps to 1 if nothing near
    for (int g = 0; g < n_kept; ++g) {
        const float4 sg = sseg[g];   // broadcast ds_read_b128
        const float2 ms = smul[g];   // broadcast ds_read_b64
        const float pvx  = px  - sg.x;
        const float pvy0 = py0 - sg.y;
        const float pvy1 = py1 - sg.y;
        const float pe   = pvx * sg.z;          // shared across the 2 pixels
        float f0 = fmaf(pvy0, sg.w, pe) * ms.x;
        float f1 = fmaf(pvy1, sg.w, pe) * ms.x;
        f0 = fminf(fmaxf(f0, 0.0f), 1.0f);      // v_med3_f32
        f1 = fminf(fmaxf(f1, 0.0f), 1.0f);
        const float dx0 = fmaf(-f0, sg.z, pvx);
        const float dy0 = fmaf(-f0, sg.w, pvy0);
        const float dx1 = fmaf(-f1, sg.z, pvx);
        const float dy1 = fmaf(-f1, sg.w, pvy1);
        const float q0 = fmaf(dy0, dy0, dx0 * dx0);
        const float q1 = fmaf(dy1, dy1, dx1 * dx1);
        acc0 = fminf(acc0, q0 * ms.y);
        acc1 = fminf(acc1, q1 * ms.y);
    }

    const float o0 = fminf(sqrtf(acc0), 1.0f);
    const float o1 = fminf(sqrtf(acc1), 1.0f);
    *reinterpret_cast<float2*>(out + (pi << 9) + pj) = make_float2(o0, o1);
}

extern "C" void kernel_launch(void* const* d_in, const int* in_sizes, int n_in,
                              void* d_out, int out_size, void* d_ws, size_t ws_size,
                              hipStream_t stream) {
    const float* strokes = (const float*)d_in[0];
    const float* thick   = (const float*)d_in[1];
    float* out = (float*)d_out;
    hipLaunchKernelGGL(render_kernel, dim3(512), dim3(256), 0, stream,
                       strokes, thick, out);
}